// Round 15
// baseline (164.231 us; speedup 1.0000x reference)
//
#include <hip/hip_runtime.h>
#include <stdint.h>

typedef __attribute__((ext_vector_type(8))) short short8;
typedef __attribute__((ext_vector_type(4))) float f32x4;

__device__ __forceinline__ float bf2f(unsigned short u) {
  union { unsigned int i; float f; } x; x.i = ((unsigned int)u) << 16; return x.f;
}
__device__ __forceinline__ unsigned short f2bf(float f) {
  union { float f; unsigned int i; } x; x.f = f;
  unsigned int u = x.i;
  unsigned int r = (u + 0x7FFFu + ((u >> 16) & 1u)) >> 16;
  return (unsigned short)r;
}
__device__ __forceinline__ unsigned int fmono(float f) {
  unsigned int u = __float_as_uint(f);
  return (u & 0x80000000u) ? ~u : (u | 0x80000000u);
}

typedef const __attribute__((address_space(1))) void* gas_ptr;
typedef __attribute__((address_space(3))) void* las_ptr;
__device__ __forceinline__ void gld_lds16(const void* g, void* l) {
  __builtin_amdgcn_global_load_lds((gas_ptr)g, (las_ptr)l, 16, 0, 0);
}

// ---------------- merged convert: x (fp32->bf16) + weights (transpose+convert) ----------------
__global__ void cvt_kernel(const float* __restrict__ x, unsigned short* __restrict__ xbf,
                           const float* __restrict__ kern, unsigned short* __restrict__ wbfT) {
  int bid = blockIdx.x;
  if (bid < 4096) {
    int i = bid * 256 + threadIdx.x;
    const float4* xp = (const float4*)x;
    float4 a = xp[2 * i], b = xp[2 * i + 1];
    union { unsigned short us[8]; uint4 v; } o;
    o.us[0] = f2bf(a.x); o.us[1] = f2bf(a.y); o.us[2] = f2bf(a.z); o.us[3] = f2bf(a.w);
    o.us[4] = f2bf(b.x); o.us[5] = f2bf(b.y); o.us[6] = f2bf(b.z); o.us[7] = f2bf(b.w);
    ((uint4*)xbf)[i] = o.v;
  } else {
    __shared__ float tile[32][33];
    int b = bid - 4096;            // 0..767
    int w = b >> 8;                // 0..2
    int r2 = b & 255;
    int d0 = (r2 >> 4) * 32, o0 = (r2 & 15) * 32;
    int c = threadIdx.x & 31, r0 = threadIdx.x >> 5;
    const float* kp = kern + (size_t)w * 262144;
    unsigned short* op = wbfT + (size_t)w * 262144;
#pragma unroll
    for (int i = 0; i < 4; ++i)
      tile[r0 + 8 * i][c] = kp[(size_t)(d0 + r0 + 8 * i) * 512 + o0 + c];
    __syncthreads();
#pragma unroll
    for (int i = 0; i < 4; ++i)
      op[(size_t)(o0 + r0 + 8 * i) * 512 + d0 + c] = f2bf(tile[c][r0 + 8 * i]);
  }
}

// ============= 256xBNT GEMM body, C = A * B^T, bf16 MFMA (r4/r10 schedule) =============
// A: [M][K] bf16 row-major. B: [N][K] bf16 row-major (B^T layout).
// MODE 0: QK fused-exp: writes bf16 exp(v*scale) to C (pure per-lane epilogue).
// MODE 1: bf16 VT-mapped (m=o, n=token) [coalesced in n].
// MODE 2: PV fused-normalize: ones-column MFMA accumulates row sums of A (= P~);
//         epilogue writes fp32 v/rs, 0 at row c0 (read from keyp).
// MODE 3: merged QK-proj N=1024 (n<512 -> WQ*0.125, else WK).
// Wave geometry: BNT=256 -> (2M,4N); BNT=128 -> (4M,2N). NF=4 both.
// bid in [0,nwg), nwg%8==0 (bijective XCD swizzle).
template <int MODE, int BNT>
__device__ __forceinline__ void gemm_body(
    int bid, int nwg, char* lds,
    const unsigned short* __restrict__ A, const unsigned short* __restrict__ B,
    void* __restrict__ C, int M, int N, int K,
    long long Abat, long long Bbat, long long Cbat, float scale,
    const unsigned long long* __restrict__ keyp) {
  constexpr int LB = BNT / 128;         // gld_lds per B half-tile (2 or 1)
  constexpr int BHB = (BNT / 2) * 128;  // bytes per B half-tile
  constexpr int PBUF = 32768 + 2 * BHB; // K-tile buffer (A-lo,A-hi,B-lo,B-hi)
  constexpr int WM = (BNT == 128) ? 4 : 2;  // waves in M
  constexpr int RPW = 256 / WM;             // rows per wave (64 or 128)
  constexpr int MF = RPW / 16;              // 16-row fragments per wave (4 or 8)
  constexpr int IC = MF / 4;                // row-frags per phase (1 or 2)

  const int tx = N / BNT, ty = M >> 8;
  const int swz = (bid & 7) * (nwg >> 3) + (bid >> 3);  // bijective, nwg%8==0
  const int tpz = tx * ty;
  const int z = swz / tpz;
  const int rem = swz - z * tpz;
  const int by = rem / tx;
  const int bx = rem - by * tx;
  const unsigned short* Ab = A + (size_t)z * (size_t)Abat;
  const unsigned short* Bb = B + (size_t)z * (size_t)Bbat;
  const int bm0 = by << 8;
  const int bn0 = bx * BNT;

  const int tid = threadIdx.x, lane = tid & 63, w = tid >> 6;
  const int wr = (WM == 4) ? (w >> 1) : (w >> 2);
  const int wc = (WM == 4) ? (w & 1) : (w & 3);
  const int ln15 = lane & 15, hi = lane >> 4;
  const unsigned xorv = (unsigned)(lane & 7) << 4;
  const unsigned K2 = (unsigned)K * 2;

  const char* gsrc[4];
  gsrc[0] = (const char*)(Ab + (size_t)bm0 * K);
  gsrc[1] = (const char*)(Ab + (size_t)(bm0 + 128) * K);
  gsrc[2] = (const char*)(Bb + (size_t)bn0 * K);
  gsrc[3] = (const char*)(Bb + (size_t)(bn0 + BNT / 2) * K);
  const int hoff_[4] = {0, 16384, 32768, 32768 + BHB};
  unsigned op0 = (unsigned)(w * 1024 + lane * 16);
  unsigned op1 = op0 + 8192;
  const unsigned soff0 = (op0 >> 7) * K2 + ((op0 & 127) ^ (((op0 >> 7) & 7) << 4));
  const unsigned soff1 = (op1 >> 7) * K2 + ((op1 & 127) ^ (((op1 >> 7) & 7) << 4));
  const int lb0 = w * 1024, lb1 = 8192 + w * 1024;

#define STAGE(h, pp, kb)                                              \
  do {                                                                \
    char* lp_ = lds + (pp) * PBUF + hoff_[h];                         \
    const char* gp_ = gsrc[h] + ((unsigned)(kb) << 1);                \
    gld_lds16(gp_ + soff0, lp_ + lb0);                                \
    if ((h) < 2 || LB == 2) gld_lds16(gp_ + soff1, lp_ + lb1);        \
  } while (0)

  f32x4 acc[MF][4];
#pragma unroll
  for (int i = 0; i < MF; ++i)
#pragma unroll
    for (int j = 0; j < 4; ++j) acc[i][j] = (f32x4){0.f, 0.f, 0.f, 0.f};

  // MODE 2: row-sum accumulators via ones-column MFMA (same C/D row mapping)
  f32x4 accs1[MF];
  short8 onesf;
  if constexpr (MODE == 2) {
#pragma unroll
    for (int i = 0; i < MF; ++i) accs1[i] = (f32x4){0.f, 0.f, 0.f, 0.f};
#pragma unroll
    for (int j = 0; j < 8; ++j) onesf[j] = (short)0x3F80;  // bf16 1.0
  }

  const int NT = K >> 6;
  // prologue: tile0 all 4 half-tiles (depth-1 pipeline)
  STAGE(0, 0, 0);
  STAGE(1, 0, 0);
  STAGE(2, 0, 0);
  STAGE(3, 0, 0);
  asm volatile("s_waitcnt vmcnt(0)" ::: "memory");
  __builtin_amdgcn_s_barrier();

  short8 bfrag[4][2];
  for (int t = 0; t < NT; ++t) {
    const int p = t & 1;
    char* Lp = lds + p * PBUF;
    const int kN = (t + 1) << 6;
    const bool sN = (t + 1 < NT);
#pragma unroll
    for (int q = 0; q < 4; ++q) {
      if (q == 0) {
        // B fragments for the whole tile, held in registers
#pragma unroll
        for (int nf = 0; nf < 4; ++nf) {
          const int col = wc * 64 + nf * 16 + ln15;  // row within BNT B-tile
          const char* bp = Lp + 32768 + ((col >= BNT / 2) ? BHB : 0) +
                           (col & (BNT / 2 - 1)) * 128;
#pragma unroll
          for (int k = 0; k < 2; ++k)
            bfrag[nf][k] = *(const short8*)(bp + (((unsigned)(k * 64 + hi * 16)) ^ xorv));
        }
      }
      short8 af[IC][2];
#pragma unroll
      for (int i = 0; i < IC; ++i) {
        const int row = wr * RPW + (q * IC + i) * 16 + ln15;  // 0..255
        const char* ap = Lp + ((row >> 7) << 14) + (row & 127) * 128;
#pragma unroll
        for (int k = 0; k < 2; ++k)
          af[i][k] = *(const short8*)(ap + (((unsigned)(k * 64 + hi * 16)) ^ xorv));
      }
      // stage next tile early (q0/q1) so vmcnt(0) at tile end is residual-only
      if (q == 0 && sN) { STAGE(0, p ^ 1, kN); STAGE(2, p ^ 1, kN); }
      if (q == 1 && sN) { STAGE(1, p ^ 1, kN); STAGE(3, p ^ 1, kN); }
      __builtin_amdgcn_s_setprio(1);
#pragma unroll
      for (int i = 0; i < IC; ++i) {
#pragma unroll
        for (int nf = 0; nf < 4; ++nf)
#pragma unroll
          for (int k = 0; k < 2; ++k)
            acc[q * IC + i][nf] = __builtin_amdgcn_mfma_f32_16x16x32_bf16(
                af[i][k], bfrag[nf][k], acc[q * IC + i][nf], 0, 0, 0);
        if constexpr (MODE == 2) {
#pragma unroll
          for (int k = 0; k < 2; ++k)
            accs1[q * IC + i] = __builtin_amdgcn_mfma_f32_16x16x32_bf16(
                af[i][k], onesf, accs1[q * IC + i], 0, 0, 0);
        }
      }
      __builtin_amdgcn_s_setprio(0);
    }
    asm volatile("s_waitcnt vmcnt(0) lgkmcnt(0)" ::: "memory");
    __builtin_amdgcn_s_barrier();
  }
#undef STAGE

  // epilogue
  const int rg = hi * 4;
  const int cc = ln15;
  int c0 = 0;
  if constexpr (MODE == 2) c0 = (int)(unsigned int)(*keyp & 0xffffffffULL);
#pragma unroll
  for (int mf = 0; mf < MF; ++mf) {
#pragma unroll
    for (int nf = 0; nf < 4; ++nf) {
#pragma unroll
      for (int r = 0; r < 4; ++r) {
        int m = bm0 + wr * RPW + mf * 16 + rg + r;
        int n = bn0 + wc * 64 + nf * 16 + cc;
        float v = acc[mf][nf][r];
        if (MODE == 0) {
          ((unsigned short*)C)[(size_t)z * (size_t)Cbat + (size_t)m * N + n] =
              f2bf(__expf(v * scale));
        } else if (MODE == 1) {
          int bb = n >> 11, tl = n & 2047;
          ((unsigned short*)C)[((size_t)(bb * 512 + m) << 11) + tl] = f2bf(v);
        } else if (MODE == 2) {
          float lv = (m == c0) ? 0.f : (1.f / accs1[mf][r]);
          ((float*)C)[(size_t)z * (size_t)Cbat + (size_t)m * N + n] = v * lv;
        } else {
          size_t idx = (size_t)(n >> 9) * 8388608 + (size_t)m * 512 + (n & 511);
          float sc = (n >> 9) ? 1.0f : 0.125f;
          ((unsigned short*)C)[idx] = f2bf(v * sc);
        }
      }
    }
  }
}

// standalone GEMM kernels (QK, PV)
template <int MODE, int BNT>
__global__ __launch_bounds__(512, 1) void gemm8p(
    const unsigned short* __restrict__ A, const unsigned short* __restrict__ B,
    void* __restrict__ C, int M, int N, int K,
    long long Abat, long long Bbat, long long Cbat, float scale,
    const unsigned long long* __restrict__ keyp) {
  constexpr int PBUF = 32768 + 2 * ((BNT / 2) * 128);
  __shared__ __align__(16) char lds[2 * PBUF];
  gemm_body<MODE, BNT>(blockIdx.x, gridDim.x, lds, A, B, C, M, N, K,
                       Abat, Bbat, Cbat, scale, keyp);
}

// fused projections: bid<256 -> QK-proj (MODE 3, BNT=256, nwg=256);
// bid>=256 -> V-proj (MODE 1, BNT=256, nwg=128: 128 blocks, 2x work/block vs
// BNT=128 -> halves fill/drain count and drops fused grid 512->384).
// Disjoint outputs (WQ|WK vs VT), shared read-only inputs.
__global__ __launch_bounds__(512, 1) void proj_fused(
    const unsigned short* __restrict__ xbf, const unsigned short* __restrict__ wbfT,
    unsigned short* __restrict__ WQ, unsigned short* __restrict__ VT) {
  __shared__ __align__(16) char lds[131072];
  int bid = blockIdx.x;
  if (bid < 256) {
    gemm_body<3, 256>(bid, 256, lds, xbf, wbfT, WQ, 16384, 1024, 512,
                      0, 0, 0, 1.0f, nullptr);
  } else {
    gemm_body<1, 256>(bid - 256, 128, lds, wbfT + 524288, xbf, VT, 512, 16384, 512,
                      0, 0, 0, 1.0f, nullptr);
  }
}

// ---------------- Ksum partials: partial[j][o] = sum_{t in chunk j} WK[0][t][o] ----------------
__global__ void ksum_kernel(const unsigned short* __restrict__ WK, float* __restrict__ partial) {
  int col = threadIdx.x;
  int t0 = blockIdx.x * 64;
  float s = 0.f;
  for (int t = 0; t < 64; ++t) s += bf2f(WK[(size_t)(t0 + t) * 512 + col]);
  partial[blockIdx.x * 512 + col] = s;
}

// ---------------- rs[s] = WQ[0][s] . Ksum ; global argmin via packed atomicMin ----------------
__global__ void rs_argmin_kernel(const unsigned short* __restrict__ WQ,
                                 const float* __restrict__ partial,
                                 unsigned long long* __restrict__ key) {
  __shared__ __align__(16) float ks[512];
  int tid = threadIdx.x;
  for (int c = tid; c < 512; c += 256) {
    float s = 0.f;
#pragma unroll
    for (int j = 0; j < 32; ++j) s += partial[j * 512 + c];
    ks[c] = s;
  }
  __syncthreads();
  int w = tid >> 6, lane = tid & 63;
  float4 ka = *(const float4*)&ks[lane * 8];
  float4 kb = *(const float4*)&ks[lane * 8 + 4];
  for (int it = 0; it < 16; ++it) {
    int row = blockIdx.x * 64 + w * 16 + it;
    uint4 q = *(const uint4*)(WQ + (size_t)row * 512 + lane * 8);
    float d = 0.f;
    d += bf2f((unsigned short)(q.x & 0xffff)) * ka.x;
    d += bf2f((unsigned short)(q.x >> 16)) * ka.y;
    d += bf2f((unsigned short)(q.y & 0xffff)) * ka.z;
    d += bf2f((unsigned short)(q.y >> 16)) * ka.w;
    d += bf2f((unsigned short)(q.z & 0xffff)) * kb.x;
    d += bf2f((unsigned short)(q.z >> 16)) * kb.y;
    d += bf2f((unsigned short)(q.w & 0xffff)) * kb.z;
    d += bf2f((unsigned short)(q.w >> 16)) * kb.w;
#pragma unroll
    for (int m = 32; m; m >>= 1) d += __shfl_xor(d, m);
    if (lane == 0) {
      unsigned long long kk = ((unsigned long long)fmono(d) << 32) | (unsigned int)row;
      atomicMin(key, kk);
    }
  }
}

extern "C" void kernel_launch(void* const* d_in, const int* in_sizes, int n_in,
                              void* d_out, int out_size, void* d_ws, size_t ws_size,
                              hipStream_t stream) {
  const float* x = (const float*)d_in[0];
  const float* kern = (const float*)d_in[1];
  float* out = (float*)d_out;

  char* ws = (char*)d_ws;
  size_t off = 0;
  auto alloc = [&](size_t b) -> char* {
    char* p = ws + off;
    off += (b + 255) & ~(size_t)255;
    return p;
  };
  // NOTE: WQ and WK must be contiguous (MODE 3 writes both via one base).
  unsigned short* xbf = (unsigned short*)alloc(16384ull * 512 * 2);
  unsigned short* wbfT = (unsigned short*)alloc(3ull * 512 * 512 * 2);
  unsigned short* WQ = (unsigned short*)alloc(16384ull * 512 * 2);
  unsigned short* WK = (unsigned short*)alloc(16384ull * 512 * 2);
  unsigned short* VT = (unsigned short*)alloc(16384ull * 512 * 2);
  float* partial = (float*)alloc(32ull * 512 * 4);
  unsigned long long* key = (unsigned long long*)alloc(256);
  size_t fixed = off;
  size_t sbytes = 2048ull * 2048 * 2;
  int nb = 1;
  if (ws_size > fixed + sbytes) {
    size_t av = (ws_size - fixed) / sbytes;
    nb = av > 8 ? 8 : (int)av;
    if (nb < 1) nb = 1;
  }
  unsigned short* S = (unsigned short*)alloc(sbytes * (size_t)nb);

  hipMemsetAsync(key, 0xFF, 8, stream);

  // merged converts: blocks [0,4096) = x, [4096,4864) = weights
  cvt_kernel<<<4864, 256, 0, stream>>>(x, xbf, kern, wbfT);

  // fused projections: QK-proj (WQ*1/8 | WK) + V-proj (VT transposed, coalesced)
  proj_fused<<<384, 512, 0, stream>>>(xbf, wbfT, WQ, VT);

  // argmin of row-sums of QK[0] via Ksum trick
  ksum_kernel<<<32, 512, 0, stream>>>(WK, partial);
  rs_argmin_kernel<<<32, 256, 0, stream>>>(WQ, partial, key);

  for (int b0 = 0; b0 < 8; b0 += nb) {
    int cb = (8 - b0) < nb ? (8 - b0) : nb;
    // S = exp(Q K^T) (scale folded into Q)
    gemm8p<0, 256><<<64 * cb, 512, 0, stream>>>(
        WQ + (size_t)b0 * 2048 * 512, WK + (size_t)b0 * 2048 * 512, S,
        2048, 2048, 512, 2048ll * 512, 2048ll * 512, 2048ll * 2048, 1.0f,
        nullptr);
    // out = (P~ V) / rowsum(P~), row c0 zeroed  (rowsum fused via ones-MFMA)
    gemm8p<2, 128><<<32 * cb, 512, 0, stream>>>(
        S, VT + (size_t)b0 * 512 * 2048, out + (size_t)b0 * 2048 * 512,
        2048, 512, 2048, 2048ll * 2048, 512ll * 2048, 2048ll * 512, 1.0f,
        key);
  }
}

// Round 16
// 162.138 us; speedup vs baseline: 1.0129x; 1.0129x over previous
//
#include <hip/hip_runtime.h>
#include <stdint.h>

typedef __attribute__((ext_vector_type(8))) short short8;
typedef __attribute__((ext_vector_type(4))) float f32x4;

__device__ __forceinline__ float bf2f(unsigned short u) {
  union { unsigned int i; float f; } x; x.i = ((unsigned int)u) << 16; return x.f;
}
__device__ __forceinline__ unsigned short f2bf(float f) {
  union { float f; unsigned int i; } x; x.f = f;
  unsigned int u = x.i;
  unsigned int r = (u + 0x7FFFu + ((u >> 16) & 1u)) >> 16;
  return (unsigned short)r;
}
__device__ __forceinline__ unsigned int fmono(float f) {
  unsigned int u = __float_as_uint(f);
  return (u & 0x80000000u) ? ~u : (u | 0x80000000u);
}

typedef const __attribute__((address_space(1))) void* gas_ptr;
typedef __attribute__((address_space(3))) void* las_ptr;
__device__ __forceinline__ void gld_lds16(const void* g, void* l) {
  __builtin_amdgcn_global_load_lds((gas_ptr)g, (las_ptr)l, 16, 0, 0);
}

// ---------------- merged convert: x (fp32->bf16) + weights (transpose+convert) ----------------
__global__ void cvt_kernel(const float* __restrict__ x, unsigned short* __restrict__ xbf,
                           const float* __restrict__ kern, unsigned short* __restrict__ wbfT) {
  int bid = blockIdx.x;
  if (bid < 4096) {
    int i = bid * 256 + threadIdx.x;
    const float4* xp = (const float4*)x;
    float4 a = xp[2 * i], b = xp[2 * i + 1];
    union { unsigned short us[8]; uint4 v; } o;
    o.us[0] = f2bf(a.x); o.us[1] = f2bf(a.y); o.us[2] = f2bf(a.z); o.us[3] = f2bf(a.w);
    o.us[4] = f2bf(b.x); o.us[5] = f2bf(b.y); o.us[6] = f2bf(b.z); o.us[7] = f2bf(b.w);
    ((uint4*)xbf)[i] = o.v;
  } else {
    __shared__ float tile[32][33];
    int b = bid - 4096;            // 0..767
    int w = b >> 8;                // 0..2
    int r2 = b & 255;
    int d0 = (r2 >> 4) * 32, o0 = (r2 & 15) * 32;
    int c = threadIdx.x & 31, r0 = threadIdx.x >> 5;
    const float* kp = kern + (size_t)w * 262144;
    unsigned short* op = wbfT + (size_t)w * 262144;
#pragma unroll
    for (int i = 0; i < 4; ++i)
      tile[r0 + 8 * i][c] = kp[(size_t)(d0 + r0 + 8 * i) * 512 + o0 + c];
    __syncthreads();
#pragma unroll
    for (int i = 0; i < 4; ++i)
      op[(size_t)(o0 + r0 + 8 * i) * 512 + d0 + c] = f2bf(tile[c][r0 + 8 * i]);
  }
}

// ============= 256xBNT GEMM body, C = A * B^T, bf16 MFMA (r4/r10 schedule) =============
// A: [M][K] bf16 row-major. B: [N][K] bf16 row-major (B^T layout).
// MODE 0: QK fused-exp: writes bf16 exp(v*scale) to C (pure per-lane epilogue).
// MODE 1: bf16 VT-mapped (m=o, n=token) [coalesced in n].
// MODE 2: PV fused-normalize: ones-column MFMA accumulates row sums of A (= P~);
//         epilogue writes fp32 v/rs, 0 at row c0 (read from keyp).
// MODE 3: merged QK-proj N=1024 (n<512 -> WQ*0.125, else WK).
// Wave geometry: BNT=256 -> (2M,4N); BNT=128 -> (4M,2N). NF=4 both.
// bid in [0,nwg), nwg%8==0 (bijective XCD swizzle).
template <int MODE, int BNT>
__device__ __forceinline__ void gemm_body(
    int bid, int nwg, char* lds,
    const unsigned short* __restrict__ A, const unsigned short* __restrict__ B,
    void* __restrict__ C, int M, int N, int K,
    long long Abat, long long Bbat, long long Cbat, float scale,
    const unsigned long long* __restrict__ keyp) {
  constexpr int LB = BNT / 128;         // gld_lds per B half-tile (2 or 1)
  constexpr int BHB = (BNT / 2) * 128;  // bytes per B half-tile
  constexpr int PBUF = 32768 + 2 * BHB; // K-tile buffer (A-lo,A-hi,B-lo,B-hi)
  constexpr int WM = (BNT == 128) ? 4 : 2;  // waves in M
  constexpr int RPW = 256 / WM;             // rows per wave (64 or 128)
  constexpr int MF = RPW / 16;              // 16-row fragments per wave (4 or 8)
  constexpr int IC = MF / 4;                // row-frags per phase (1 or 2)

  const int tx = N / BNT, ty = M >> 8;
  const int swz = (bid & 7) * (nwg >> 3) + (bid >> 3);  // bijective, nwg%8==0
  const int tpz = tx * ty;
  const int z = swz / tpz;
  const int rem = swz - z * tpz;
  const int by = rem / tx;
  const int bx = rem - by * tx;
  const unsigned short* Ab = A + (size_t)z * (size_t)Abat;
  const unsigned short* Bb = B + (size_t)z * (size_t)Bbat;
  const int bm0 = by << 8;
  const int bn0 = bx * BNT;

  const int tid = threadIdx.x, lane = tid & 63, w = tid >> 6;
  const int wr = (WM == 4) ? (w >> 1) : (w >> 2);
  const int wc = (WM == 4) ? (w & 1) : (w & 3);
  const int ln15 = lane & 15, hi = lane >> 4;
  const unsigned xorv = (unsigned)(lane & 7) << 4;
  const unsigned K2 = (unsigned)K * 2;

  const char* gsrc[4];
  gsrc[0] = (const char*)(Ab + (size_t)bm0 * K);
  gsrc[1] = (const char*)(Ab + (size_t)(bm0 + 128) * K);
  gsrc[2] = (const char*)(Bb + (size_t)bn0 * K);
  gsrc[3] = (const char*)(Bb + (size_t)(bn0 + BNT / 2) * K);
  const int hoff_[4] = {0, 16384, 32768, 32768 + BHB};
  unsigned op0 = (unsigned)(w * 1024 + lane * 16);
  unsigned op1 = op0 + 8192;
  const unsigned soff0 = (op0 >> 7) * K2 + ((op0 & 127) ^ (((op0 >> 7) & 7) << 4));
  const unsigned soff1 = (op1 >> 7) * K2 + ((op1 & 127) ^ (((op1 >> 7) & 7) << 4));
  const int lb0 = w * 1024, lb1 = 8192 + w * 1024;

#define STAGE(h, pp, kb)                                              \
  do {                                                                \
    char* lp_ = lds + (pp) * PBUF + hoff_[h];                         \
    const char* gp_ = gsrc[h] + ((unsigned)(kb) << 1);                \
    gld_lds16(gp_ + soff0, lp_ + lb0);                                \
    if ((h) < 2 || LB == 2) gld_lds16(gp_ + soff1, lp_ + lb1);        \
  } while (0)

  f32x4 acc[MF][4];
#pragma unroll
  for (int i = 0; i < MF; ++i)
#pragma unroll
    for (int j = 0; j < 4; ++j) acc[i][j] = (f32x4){0.f, 0.f, 0.f, 0.f};

  // MODE 2: row-sum accumulators via ones-column MFMA (same C/D row mapping)
  f32x4 accs1[MF];
  short8 onesf;
  if constexpr (MODE == 2) {
#pragma unroll
    for (int i = 0; i < MF; ++i) accs1[i] = (f32x4){0.f, 0.f, 0.f, 0.f};
#pragma unroll
    for (int j = 0; j < 8; ++j) onesf[j] = (short)0x3F80;  // bf16 1.0
  }

  const int NT = K >> 6;
  // prologue: tile0 all 4 half-tiles (depth-1 pipeline)
  STAGE(0, 0, 0);
  STAGE(1, 0, 0);
  STAGE(2, 0, 0);
  STAGE(3, 0, 0);
  asm volatile("s_waitcnt vmcnt(0)" ::: "memory");
  __builtin_amdgcn_s_barrier();

  short8 bfrag[4][2];
  for (int t = 0; t < NT; ++t) {
    const int p = t & 1;
    char* Lp = lds + p * PBUF;
    const int kN = (t + 1) << 6;
    const bool sN = (t + 1 < NT);
#pragma unroll
    for (int q = 0; q < 4; ++q) {
      if (q == 0) {
        // B fragments for the whole tile, held in registers
#pragma unroll
        for (int nf = 0; nf < 4; ++nf) {
          const int col = wc * 64 + nf * 16 + ln15;  // row within BNT B-tile
          const char* bp = Lp + 32768 + ((col >= BNT / 2) ? BHB : 0) +
                           (col & (BNT / 2 - 1)) * 128;
#pragma unroll
          for (int k = 0; k < 2; ++k)
            bfrag[nf][k] = *(const short8*)(bp + (((unsigned)(k * 64 + hi * 16)) ^ xorv));
        }
      }
      short8 af[IC][2];
#pragma unroll
      for (int i = 0; i < IC; ++i) {
        const int row = wr * RPW + (q * IC + i) * 16 + ln15;  // 0..255
        const char* ap = Lp + ((row >> 7) << 14) + (row & 127) * 128;
#pragma unroll
        for (int k = 0; k < 2; ++k)
          af[i][k] = *(const short8*)(ap + (((unsigned)(k * 64 + hi * 16)) ^ xorv));
      }
      // stage next tile early (q0/q1) so vmcnt(0) at tile end is residual-only
      if (q == 0 && sN) { STAGE(0, p ^ 1, kN); STAGE(2, p ^ 1, kN); }
      if (q == 1 && sN) { STAGE(1, p ^ 1, kN); STAGE(3, p ^ 1, kN); }
      __builtin_amdgcn_s_setprio(1);
#pragma unroll
      for (int i = 0; i < IC; ++i) {
#pragma unroll
        for (int nf = 0; nf < 4; ++nf)
#pragma unroll
          for (int k = 0; k < 2; ++k)
            acc[q * IC + i][nf] = __builtin_amdgcn_mfma_f32_16x16x32_bf16(
                af[i][k], bfrag[nf][k], acc[q * IC + i][nf], 0, 0, 0);
        if constexpr (MODE == 2) {
#pragma unroll
          for (int k = 0; k < 2; ++k)
            accs1[q * IC + i] = __builtin_amdgcn_mfma_f32_16x16x32_bf16(
                af[i][k], onesf, accs1[q * IC + i], 0, 0, 0);
        }
      }
      __builtin_amdgcn_s_setprio(0);
    }
    asm volatile("s_waitcnt vmcnt(0) lgkmcnt(0)" ::: "memory");
    __builtin_amdgcn_s_barrier();
  }
#undef STAGE

  // epilogue
  const int rg = hi * 4;
  const int cc = ln15;
  int c0 = 0;
  if constexpr (MODE == 2) c0 = (int)(unsigned int)(*keyp & 0xffffffffULL);
#pragma unroll
  for (int mf = 0; mf < MF; ++mf) {
#pragma unroll
    for (int nf = 0; nf < 4; ++nf) {
#pragma unroll
      for (int r = 0; r < 4; ++r) {
        int m = bm0 + wr * RPW + mf * 16 + rg + r;
        int n = bn0 + wc * 64 + nf * 16 + cc;
        float v = acc[mf][nf][r];
        if (MODE == 0) {
          ((unsigned short*)C)[(size_t)z * (size_t)Cbat + (size_t)m * N + n] =
              f2bf(__expf(v * scale));
        } else if (MODE == 1) {
          int bb = n >> 11, tl = n & 2047;
          ((unsigned short*)C)[((size_t)(bb * 512 + m) << 11) + tl] = f2bf(v);
        } else if (MODE == 2) {
          float lv = (m == c0) ? 0.f : (1.f / accs1[mf][r]);
          ((float*)C)[(size_t)z * (size_t)Cbat + (size_t)m * N + n] = v * lv;
        } else {
          size_t idx = (size_t)(n >> 9) * 8388608 + (size_t)m * 512 + (n & 511);
          float sc = (n >> 9) ? 1.0f : 0.125f;
          ((unsigned short*)C)[idx] = f2bf(v * sc);
        }
      }
    }
  }
}

// standalone GEMM kernels (QK, PV)
template <int MODE, int BNT>
__global__ __launch_bounds__(512, 1) void gemm8p(
    const unsigned short* __restrict__ A, const unsigned short* __restrict__ B,
    void* __restrict__ C, int M, int N, int K,
    long long Abat, long long Bbat, long long Cbat, float scale,
    const unsigned long long* __restrict__ keyp) {
  constexpr int PBUF = 32768 + 2 * ((BNT / 2) * 128);
  __shared__ __align__(16) char lds[2 * PBUF];
  gemm_body<MODE, BNT>(blockIdx.x, gridDim.x, lds, A, B, C, M, N, K,
                       Abat, Bbat, Cbat, scale, keyp);
}

// fused projections: bid<256 -> QK-proj (MODE 3, BNT=256); bid>=256 -> V-proj
// (MODE 1, BNT=128). Disjoint outputs (WQ|WK vs VT), shared read-only inputs.
__global__ __launch_bounds__(512, 1) void proj_fused(
    const unsigned short* __restrict__ xbf, const unsigned short* __restrict__ wbfT,
    unsigned short* __restrict__ WQ, unsigned short* __restrict__ VT) {
  __shared__ __align__(16) char lds[131072];
  int bid = blockIdx.x;
  if (bid < 256) {
    gemm_body<3, 256>(bid, 256, lds, xbf, wbfT, WQ, 16384, 1024, 512,
                      0, 0, 0, 1.0f, nullptr);
  } else {
    gemm_body<1, 128>(bid - 256, 256, lds, wbfT + 524288, xbf, VT, 512, 16384, 512,
                      0, 0, 0, 1.0f, nullptr);
  }
}

// ---------------- Ksum partials: partial[j][o] = sum_{t in chunk j} WK[0][t][o] ----------------
__global__ void ksum_kernel(const unsigned short* __restrict__ WK, float* __restrict__ partial) {
  int col = threadIdx.x;
  int t0 = blockIdx.x * 64;
  float s = 0.f;
  for (int t = 0; t < 64; ++t) s += bf2f(WK[(size_t)(t0 + t) * 512 + col]);
  partial[blockIdx.x * 512 + col] = s;
}

// ---------------- rs[s] = WQ[0][s] . Ksum ; global argmin via packed atomicMin ----------------
__global__ void rs_argmin_kernel(const unsigned short* __restrict__ WQ,
                                 const float* __restrict__ partial,
                                 unsigned long long* __restrict__ key) {
  __shared__ __align__(16) float ks[512];
  int tid = threadIdx.x;
  for (int c = tid; c < 512; c += 256) {
    float s = 0.f;
#pragma unroll
    for (int j = 0; j < 32; ++j) s += partial[j * 512 + c];
    ks[c] = s;
  }
  __syncthreads();
  int w = tid >> 6, lane = tid & 63;
  float4 ka = *(const float4*)&ks[lane * 8];
  float4 kb = *(const float4*)&ks[lane * 8 + 4];
  for (int it = 0; it < 16; ++it) {
    int row = blockIdx.x * 64 + w * 16 + it;
    uint4 q = *(const uint4*)(WQ + (size_t)row * 512 + lane * 8);
    float d = 0.f;
    d += bf2f((unsigned short)(q.x & 0xffff)) * ka.x;
    d += bf2f((unsigned short)(q.x >> 16)) * ka.y;
    d += bf2f((unsigned short)(q.y & 0xffff)) * ka.z;
    d += bf2f((unsigned short)(q.y >> 16)) * ka.w;
    d += bf2f((unsigned short)(q.z & 0xffff)) * kb.x;
    d += bf2f((unsigned short)(q.z >> 16)) * kb.y;
    d += bf2f((unsigned short)(q.w & 0xffff)) * kb.z;
    d += bf2f((unsigned short)(q.w >> 16)) * kb.w;
#pragma unroll
    for (int m = 32; m; m >>= 1) d += __shfl_xor(d, m);
    if (lane == 0) {
      unsigned long long kk = ((unsigned long long)fmono(d) << 32) | (unsigned int)row;
      atomicMin(key, kk);
    }
  }
}

extern "C" void kernel_launch(void* const* d_in, const int* in_sizes, int n_in,
                              void* d_out, int out_size, void* d_ws, size_t ws_size,
                              hipStream_t stream) {
  const float* x = (const float*)d_in[0];
  const float* kern = (const float*)d_in[1];
  float* out = (float*)d_out;

  char* ws = (char*)d_ws;
  size_t off = 0;
  auto alloc = [&](size_t b) -> char* {
    char* p = ws + off;
    off += (b + 255) & ~(size_t)255;
    return p;
  };
  // NOTE: WQ and WK must be contiguous (MODE 3 writes both via one base).
  unsigned short* xbf = (unsigned short*)alloc(16384ull * 512 * 2);
  unsigned short* wbfT = (unsigned short*)alloc(3ull * 512 * 512 * 2);
  unsigned short* WQ = (unsigned short*)alloc(16384ull * 512 * 2);
  unsigned short* WK = (unsigned short*)alloc(16384ull * 512 * 2);
  unsigned short* VT = (unsigned short*)alloc(16384ull * 512 * 2);
  float* partial = (float*)alloc(32ull * 512 * 4);
  unsigned long long* key = (unsigned long long*)alloc(256);
  size_t fixed = off;
  size_t sbytes = 2048ull * 2048 * 2;
  int nb = 1;
  if (ws_size > fixed + sbytes) {
    size_t av = (ws_size - fixed) / sbytes;
    nb = av > 8 ? 8 : (int)av;
    if (nb < 1) nb = 1;
  }
  unsigned short* S = (unsigned short*)alloc(sbytes * (size_t)nb);

  hipMemsetAsync(key, 0xFF, 8, stream);

  // merged converts: blocks [0,4096) = x, [4096,4864) = weights
  cvt_kernel<<<4864, 256, 0, stream>>>(x, xbf, kern, wbfT);

  // fused projections: QK-proj (WQ*1/8 | WK) + V-proj (VT transposed, coalesced)
  proj_fused<<<512, 512, 0, stream>>>(xbf, wbfT, WQ, VT);

  // argmin of row-sums of QK[0] via Ksum trick
  ksum_kernel<<<32, 512, 0, stream>>>(WK, partial);
  rs_argmin_kernel<<<32, 256, 0, stream>>>(WQ, partial, key);

  for (int b0 = 0; b0 < 8; b0 += nb) {
    int cb = (8 - b0) < nb ? (8 - b0) : nb;
    // S = exp(Q K^T) (scale folded into Q)
    gemm8p<0, 256><<<64 * cb, 512, 0, stream>>>(
        WQ + (size_t)b0 * 2048 * 512, WK + (size_t)b0 * 2048 * 512, S,
        2048, 2048, 512, 2048ll * 512, 2048ll * 512, 2048ll * 2048, 1.0f,
        nullptr);
    // out = (P~ V) / rowsum(P~), row c0 zeroed  (rowsum fused via ones-MFMA)
    gemm8p<2, 128><<<32 * cb, 512, 0, stream>>>(
        S, VT + (size_t)b0 * 512 * 2048, out + (size_t)b0 * 2048 * 512,
        2048, 512, 2048, 2048ll * 2048, 512ll * 2048, 2048ll * 512, 1.0f,
        key);
  }
}